// Round 6
// baseline (144.956 us; speedup 1.0000x reference)
//
#include <hip/hip_runtime.h>
#include <hip/hip_bf16.h>
#include <stdint.h>

#define SS 4096
#define DD 256
#define HH 4
#define KK 64
#define ALPHA 0.18033688011112042f  // 0.125 * log2(e)

typedef float f32x4 __attribute__((ext_vector_type(4)));
typedef short s16x8 __attribute__((ext_vector_type(8)));
typedef unsigned int u32;

__device__ __forceinline__ unsigned short f2bf(float x) {
  union { float f; unsigned u; } v; v.f = x;
  unsigned r = v.u + 0x7fffu + ((v.u >> 16) & 1u);
  return (unsigned short)(r >> 16);
}

__device__ __forceinline__ u32 cvtpk(float lo, float hi) {
  u32 r;
  asm("v_cvt_pk_bf16_f32 %0, %1, %2" : "=v"(r) : "v"(lo), "v"(hi));
  return r;
}

__device__ __forceinline__ void gl_lds16(const unsigned short* g, unsigned short* l) {
  __builtin_amdgcn_global_load_lds(
      (const __attribute__((address_space(1))) u32*)g,
      (__attribute__((address_space(3))) u32*)l, 16, 0, 0);
}

// ---------------- Kernel 0: weight prep ----------------
__global__ void wprep(const float* __restrict__ Wq, const float* __restrict__ Wk,
                      const float* __restrict__ Wv, const float* __restrict__ Wo,
                      unsigned short* __restrict__ Wt, unsigned short* __restrict__ Wot)
{
  const int blk = blockIdx.x, t = threadIdx.x;
  const int rsub = t >> 4;
  const int c0 = (t & 15) * 16;
  if (blk < 48) {
    const int n = blk * 16 + rsub;               // 0..767
    const float* W = (n < 256) ? Wq : ((n < 512) ? Wk : Wv);
    const int nn = n & 255;
    const float sc = (n < 256) ? ALPHA : 1.0f;
    for (int c = c0; c < c0 + 16; ++c)
      Wt[(size_t)n * 256 + c] = f2bf(sc * W[(size_t)c * 256 + nn]);
  } else {
    const int d = (blk - 48) * 16 + rsub;        // 0..255
    for (int c = c0; c < c0 + 16; ++c)
      Wot[(size_t)d * 256 + c] = f2bf(Wo[(size_t)c * 256 + d]);
  }
}

// ---------------- Kernel 1: QKV projection (bf16 MFMA, no LDS) ----------------
__global__ __launch_bounds__(384, 3) void qkv_mfma(
    const float* __restrict__ query, const float* __restrict__ value,
    const unsigned short* __restrict__ Wt,
    const float* __restrict__ bq, const float* __restrict__ bk,
    const float* __restrict__ bv,
    unsigned short* __restrict__ qb, unsigned short* __restrict__ kbs,
    unsigned short* __restrict__ vts)
{
  const int t = threadIdx.x;
  const int w = t >> 6, l = t & 63, lr = l & 15, grp = l >> 4;
  const long r0 = (long)blockIdx.x * 32;
  const int n0 = w * 128;
  const int mat = w >> 1;

  const float* X = (mat == 0) ? query : value;

  f32x4 acc[2][8] = {};

  #pragma unroll 2
  for (int k0 = 0; k0 < 256; k0 += 32) {
    s16x8 bfr[2];
    #pragma unroll
    for (int mt = 0; mt < 2; ++mt) {
      const float* xp = X + (r0 + mt * 16 + lr) * 256 + k0 + grp * 8;
      f32x4 x0 = *(const f32x4*)xp;
      f32x4 x1 = *(const f32x4*)(xp + 4);
      union { u32 wd[4]; s16x8 v; } bb;
      bb.wd[0] = cvtpk(x0[0], x0[1]);
      bb.wd[1] = cvtpk(x0[2], x0[3]);
      bb.wd[2] = cvtpk(x1[0], x1[1]);
      bb.wd[3] = cvtpk(x1[2], x1[3]);
      bfr[mt] = bb.v;
    }
    if (mat == 2) {
      #pragma unroll
      for (int nt = 0; nt < 8; ++nt) {
        s16x8 af = *(const s16x8*)(Wt + (size_t)(n0 + nt * 16 + lr) * 256 + k0 + grp * 8);
        acc[0][nt] = __builtin_amdgcn_mfma_f32_16x16x32_bf16(bfr[0], af, acc[0][nt], 0, 0, 0);
        acc[1][nt] = __builtin_amdgcn_mfma_f32_16x16x32_bf16(bfr[1], af, acc[1][nt], 0, 0, 0);
      }
    } else {
      #pragma unroll
      for (int nt = 0; nt < 8; ++nt) {
        s16x8 af = *(const s16x8*)(Wt + (size_t)(n0 + nt * 16 + lr) * 256 + k0 + grp * 8);
        acc[0][nt] = __builtin_amdgcn_mfma_f32_16x16x32_bf16(af, bfr[0], acc[0][nt], 0, 0, 0);
        acc[1][nt] = __builtin_amdgcn_mfma_f32_16x16x32_bf16(af, bfr[1], acc[1][nt], 0, 0, 0);
      }
    }
  }

  const int b   = (int)(r0 >> 12);
  const int s0  = (int)(r0 & 4095);
  const int nl  = n0 & 255;
  const int kt  = s0 >> 6;
  const int kvb = s0 & 63;

  if (mat == 2) {
    #pragma unroll
    for (int nt = 0; nt < 8; ++nt) {
      const int n = nl + nt * 16 + lr;
      const int h = n >> 6;
      const int dk0 = n & 63;
      const int m2 = dk0 >> 4, lrv = dk0 & 15;
      const float bvn = bv[n];
      const size_t base = (size_t)(b * 4 + h) * (SS * KK) + (size_t)kt * 4096;
      const int cb = (m2 * 2 + ((kvb >> 5) & 1)) * 64 + grp * 16 + lrv;
      #pragma unroll
      for (int mt = 0; mt < 2; ++mt) {
        f32x4 o = acc[mt][nt] + bvn;
        uint2 pk2; pk2.x = cvtpk(o[0], o[1]); pk2.y = cvtpk(o[2], o[3]);
        *(uint2*)&vts[base + (size_t)cb * 8 + mt * 4] = pk2;
      }
    }
  } else {
    #pragma unroll
    for (int nt = 0; nt < 8; ++nt) {
      const int n = nl + nt * 16 + grp * 4;   // within-matrix 0..255, mult of 4
      const int h = n >> 6;
      if (mat == 0) {
        f32x4 bias = *(const f32x4*)&bq[n] * ALPHA;
        #pragma unroll
        for (int mt = 0; mt < 2; ++mt) {
          const int s = s0 + mt * 16 + lr;
          f32x4 o = acc[mt][nt] + bias;
          uint2 pk2; pk2.x = cvtpk(o[0], o[1]); pk2.y = cvtpk(o[2], o[3]);
          *(uint2*)&qb[((size_t)(b * 4 + h) * SS + s) * KK + (n & 63)] = pk2;
        }
      } else {
        const int d0 = n & 63;
        const int cc = d0 >> 5, grpk = (d0 & 31) >> 3, jlo = d0 & 7;
        f32x4 bias = *(const f32x4*)&bk[n];
        const size_t base = (size_t)(b * 4 + h) * (SS * KK) + (size_t)kt * 4096;
        #pragma unroll
        for (int mt = 0; mt < 2; ++mt) {
          const int kv = kvb + mt * 16 + lr;
          const int chunk = (((kv >> 4) * 2 + cc) * 4 + grpk) * 16 + (kv & 15);
          f32x4 o = acc[mt][nt] + bias;
          uint2 pk2; pk2.x = cvtpk(o[0], o[1]); pk2.y = cvtpk(o[2], o[3]);
          *(uint2*)&kbs[base + chunk * 8 + jlo] = pk2;
        }
      }
    }
  }
}

// ---------------- Kernel 2: causal flash attention ----------------
// 256 blocks x 256 thr (4 waves x 32 q-rows = 128-row supertile), 1 block/CU.
// Block i: bh = i&15, pr = i>>4 (0..15). Sequential pair: supertile A = pr
// (pr+1 outer steps), then B = 31-pr (32-pr outer steps) = 33 outer steps for
// EVERY block (perfect balance). Outer step stages a 128-row KV pair (32 KB,
// 8 identity gl_lds/thread), inner loop = 2 sub-tiles of 64 kv rows.
// Fixed-max exp2 softmax; l via ones-MFMA. Each wave: 2 q-tiles -> 16 LDS
// frag reads feed 36 MFMAs (2x arithmetic intensity per LDS byte vs r5).
__global__ __launch_bounds__(256, 1) void attn(
    const unsigned short* __restrict__ qb,
    const unsigned short* __restrict__ kbs,
    const unsigned short* __restrict__ vts,
    unsigned short* __restrict__ ctxb)
{
  __shared__ __align__(16) unsigned short Kl[2][8192];
  __shared__ __align__(16) unsigned short Vl[2][8192];

  const int t = threadIdx.x;
  const int w = t >> 6, l = t & 63, lr = l & 15, grp = l >> 4;

  const int i  = blockIdx.x;
  const int bh = i & 15;
  const int pr = i >> 4;            // 0..15; A = pr, B = 31-pr
  const int b = bh >> 2, h = bh & 3;

  const unsigned short* kbase = kbs + (size_t)bh * (SS * KK);
  const unsigned short* vbase = vts + (size_t)bh * (SS * KK);
  const unsigned short* qpb   = qb  + (size_t)bh * (SS * KK);

  int row0 = pr * 128;
  const int rowB = (31 - pr) * 128;

  s16x8 qf[2][2];
  #pragma unroll
  for (int q2 = 0; q2 < 2; ++q2) {
    const unsigned short* qp = qpb + (size_t)(row0 + w * 32 + q2 * 16 + lr) * KK;
    qf[q2][0] = *(const s16x8*)(qp + grp * 8);
    qf[q2][1] = *(const s16x8*)(qp + 32 + grp * 8);
  }

  s16x8 ones;
  #pragma unroll
  for (int e = 0; e < 8; ++e) ones[e] = (short)0x3F80;   // bf16 1.0
  const f32x4 minit = {-16.f, -16.f, -16.f, -16.f};

  f32x4 cacc[2][4] = {};
  f32x4 lacc[2] = {};

  // prologue: stage KV 128-pair 0 (tiles 0,1) -> buf 0. Identity chunk map:
  // chunk c = (r*4+w)*64 + l, src = base + c*16B, dst = LDS + c*16B.
  #pragma unroll
  for (int r = 0; r < 4; ++r) {
    const int cc = ((r * 4 + w) * 64 + l) * 8;
    gl_lds16(kbase + cc, &Kl[0][(r * 4 + w) * 512]);
    gl_lds16(vbase + cc, &Vl[0][(r * 4 + w) * 512]);
  }
  __syncthreads();

  for (int oss = 0; oss <= 32; ++oss) {
    const int cur = oss & 1;
    if (oss < 32) {
      const int ktn = (oss + 1 <= pr) ? 2 * (oss + 1) : 2 * (oss - pr);
      const unsigned short* ks = kbase + (size_t)ktn * 4096;
      const unsigned short* vs = vbase + (size_t)ktn * 4096;
      unsigned short* Kd = &Kl[cur ^ 1][0];
      unsigned short* Vd = &Vl[cur ^ 1][0];
      #pragma unroll
      for (int r = 0; r < 4; ++r) {
        const int cc = ((r * 4 + w) * 64 + l) * 8;
        gl_lds16(ks + cc, Kd + (r * 4 + w) * 512);
        gl_lds16(vs + cc, Vd + (r * 4 + w) * 512);
      }
    }

    const bool diag = (oss == pr) || (oss == 32);

    #pragma unroll
    for (int sub = 0; sub < 2; ++sub) {
      const unsigned short* Kb = &Kl[cur][sub * 4096];
      const unsigned short* Vb = &Vl[cur][sub * 4096];

      s16x8 kf[8];
      #pragma unroll
      for (int kc = 0; kc < 8; ++kc)
        kf[kc] = *(const s16x8*)&Kb[((kc * 4 + grp) * 16 + lr) * 8];

      // QK^T: S^T layout D[kv][q]; C-init = -16 folds the constant max
      f32x4 sc[2][4];
      #pragma unroll
      for (int q2 = 0; q2 < 2; ++q2) {
        #pragma unroll
        for (int kvt = 0; kvt < 4; ++kvt) {
          f32x4 a = __builtin_amdgcn_mfma_f32_16x16x32_bf16(kf[kvt * 2 + 0], qf[q2][0], minit, 0, 0, 0);
          a = __builtin_amdgcn_mfma_f32_16x16x32_bf16(kf[kvt * 2 + 1], qf[q2][1], a, 0, 0, 0);
          sc[q2][kvt] = a;
        }
      }

      if (diag) {
        const int toff = sub * 64;
        #pragma unroll
        for (int q2 = 0; q2 < 2; ++q2)
          #pragma unroll
          for (int kvt = 0; kvt < 4; ++kvt)
            #pragma unroll
            for (int e = 0; e < 4; ++e)
              if ((toff + kvt * 16 + grp * 4 + e) > (w * 32 + q2 * 16 + lr))
                sc[q2][kvt][e] += -1.0e9f;
      }

      #pragma unroll
      for (int q2 = 0; q2 < 2; ++q2)
        #pragma unroll
        for (int kvt = 0; kvt < 4; ++kvt)
          #pragma unroll
          for (int e = 0; e < 4; ++e)
            sc[q2][kvt][e] = exp2f(sc[q2][kvt][e]);

      s16x8 pf[2][2];
      #pragma unroll
      for (int q2 = 0; q2 < 2; ++q2) {
        #pragma unroll
        for (int kap = 0; kap < 2; ++kap) {
          union { u32 wd[4]; s16x8 v; } pu;
          pu.wd[0] = cvtpk(sc[q2][2 * kap][0], sc[q2][2 * kap][1]);
          pu.wd[1] = cvtpk(sc[q2][2 * kap][2], sc[q2][2 * kap][3]);
          pu.wd[2] = cvtpk(sc[q2][2 * kap + 1][0], sc[q2][2 * kap + 1][1]);
          pu.wd[3] = cvtpk(sc[q2][2 * kap + 1][2], sc[q2][2 * kap + 1][3]);
          pf[q2][kap] = pu.v;
        }
      }

      // PV: V frags shared across both q-tiles
      #pragma unroll
      for (int m2 = 0; m2 < 4; ++m2) {
        #pragma unroll
        for (int kap = 0; kap < 2; ++kap) {
          s16x8 vfr = *(const s16x8*)&Vb[((m2 * 2 + kap) * 64 + l) * 8];
          cacc[0][m2] = __builtin_amdgcn_mfma_f32_16x16x32_bf16(vfr, pf[0][kap], cacc[0][m2], 0, 0, 0);
          cacc[1][m2] = __builtin_amdgcn_mfma_f32_16x16x32_bf16(vfr, pf[1][kap], cacc[1][m2], 0, 0, 0);
        }
      }
      #pragma unroll
      for (int q2 = 0; q2 < 2; ++q2) {
        lacc[q2] = __builtin_amdgcn_mfma_f32_16x16x32_bf16(ones, pf[q2][0], lacc[q2], 0, 0, 0);
        lacc[q2] = __builtin_amdgcn_mfma_f32_16x16x32_bf16(ones, pf[q2][1], lacc[q2], 0, 0, 0);
      }
    }

    if (oss == pr) {  // phase-A epilogue + switch to supertile B
      #pragma unroll
      for (int q2 = 0; q2 < 2; ++q2) {
        const float inv = 1.0f / lacc[q2][0];
        unsigned short* crow = ctxb + ((size_t)b * SS + row0 + w * 32 + q2 * 16 + lr) * DD + h * KK;
        #pragma unroll
        for (int m2 = 0; m2 < 4; ++m2) {
          f32x4 o = cacc[q2][m2] * inv;
          uint2 pk2; pk2.x = cvtpk(o[0], o[1]); pk2.y = cvtpk(o[2], o[3]);
          *(uint2*)&crow[m2 * 16 + grp * 4] = pk2;
          cacc[q2][m2] = (f32x4){0.f, 0.f, 0.f, 0.f};
        }
        lacc[q2] = (f32x4){0.f, 0.f, 0.f, 0.f};
      }
      row0 = rowB;
      #pragma unroll
      for (int q2 = 0; q2 < 2; ++q2) {
        const unsigned short* qp = qpb + (size_t)(row0 + w * 32 + q2 * 16 + lr) * KK;
        qf[q2][0] = *(const s16x8*)(qp + grp * 8);
        qf[q2][1] = *(const s16x8*)(qp + 32 + grp * 8);
      }
    }
    __syncthreads();
  }

  // phase-B epilogue
  #pragma unroll
  for (int q2 = 0; q2 < 2; ++q2) {
    const float inv = 1.0f / lacc[q2][0];
    unsigned short* crow = ctxb + ((size_t)b * SS + row0 + w * 32 + q2 * 16 + lr) * DD + h * KK;
    #pragma unroll
    for (int m2 = 0; m2 < 4; ++m2) {
      f32x4 o = cacc[q2][m2] * inv;
      uint2 pk2; pk2.x = cvtpk(o[0], o[1]); pk2.y = cvtpk(o[2], o[3]);
      *(uint2*)&crow[m2 * 16 + grp * 4] = pk2;
    }
  }
}

// ---------------- Kernel 3: output projection + residual + LayerNorm (MFMA) ----------------
__global__ __launch_bounds__(256, 4) void oproj_ln(
    const unsigned short* __restrict__ ctxb, const unsigned short* __restrict__ Wot,
    const float* __restrict__ bo, const float* __restrict__ query,
    const float* __restrict__ gamma, const float* __restrict__ beta,
    float* __restrict__ out)
{
  __shared__ __align__(16) float redS[32][4];
  __shared__ __align__(16) float redQ[32][4];

  const int t = threadIdx.x;
  const int w = t >> 6, l = t & 63, lr = l & 15, grp = l >> 4;
  const long r0 = (long)blockIdx.x * 32;
  const int n0 = w * 64;

  f32x4 acc[2][4] = {};

  #pragma unroll 2
  for (int k0 = 0; k0 < 256; k0 += 32) {
    s16x8 bfr[2];
    #pragma unroll
    for (int mt = 0; mt < 2; ++mt)
      bfr[mt] = *(const s16x8*)(ctxb + (size_t)(r0 + mt * 16 + lr) * 256 + k0 + grp * 8);
    #pragma unroll
    for (int nt = 0; nt < 4; ++nt) {
      s16x8 af = *(const s16x8*)(Wot + (size_t)(n0 + nt * 16 + lr) * 256 + k0 + grp * 8);
      acc[0][nt] = __builtin_amdgcn_mfma_f32_16x16x32_bf16(af, bfr[0], acc[0][nt], 0, 0, 0);
      acc[1][nt] = __builtin_amdgcn_mfma_f32_16x16x32_bf16(af, bfr[1], acc[1][nt], 0, 0, 0);
    }
  }

  float sm[2] = {0.f, 0.f}, sq[2] = {0.f, 0.f};
  #pragma unroll
  for (int mt = 0; mt < 2; ++mt) {
    const long s = r0 + mt * 16 + lr;
    #pragma unroll
    for (int nt = 0; nt < 4; ++nt) {
      const int n = n0 + nt * 16 + grp * 4;
      f32x4 v = acc[mt][nt] + *(const f32x4*)&bo[n] + *(const f32x4*)&query[s * 256 + n];
      acc[mt][nt] = v;
      sm[mt] += v[0] + v[1] + v[2] + v[3];
      sq[mt] += v[0]*v[0] + v[1]*v[1] + v[2]*v[2] + v[3]*v[3];
    }
    sm[mt] += __shfl_xor(sm[mt], 16); sm[mt] += __shfl_xor(sm[mt], 32);
    sq[mt] += __shfl_xor(sq[mt], 16); sq[mt] += __shfl_xor(sq[mt], 32);
  }
  if (grp == 0) {
    redS[0 * 16 + lr][w] = sm[0]; redQ[0 * 16 + lr][w] = sq[0];
    redS[1 * 16 + lr][w] = sm[1]; redQ[1 * 16 + lr][w] = sq[1];
  }
  __syncthreads();

  #pragma unroll
  for (int mt = 0; mt < 2; ++mt) {
    f32x4 s4 = *(const f32x4*)&redS[mt * 16 + lr][0];
    f32x4 q4 = *(const f32x4*)&redQ[mt * 16 + lr][0];
    const float tot = s4[0] + s4[1] + s4[2] + s4[3];
    const float tq  = q4[0] + q4[1] + q4[2] + q4[3];
    const float mu  = tot * 0.00390625f;
    const float var = tq * 0.00390625f - mu * mu;
    const float rs  = rsqrtf(var + 1.0e-3f);
    const long s = r0 + mt * 16 + lr;
    #pragma unroll
    for (int nt = 0; nt < 4; ++nt) {
      const int n = n0 + nt * 16 + grp * 4;
      f32x4 g = *(const f32x4*)&gamma[n];
      f32x4 bt = *(const f32x4*)&beta[n];
      f32x4 o = (acc[mt][nt] - mu) * rs * g + bt;
      *(f32x4*)&out[s * 256 + n] = o;
    }
  }
}

extern "C" void kernel_launch(void* const* d_in, const int* in_sizes, int n_in,
                              void* d_out, int out_size, void* d_ws, size_t ws_size,
                              hipStream_t stream) {
  const float* query = (const float*)d_in[0];
  const float* value = (const float*)d_in[1];
  const float* Wq    = (const float*)d_in[2];
  const float* bq    = (const float*)d_in[3];
  const float* Wk    = (const float*)d_in[4];
  const float* bk    = (const float*)d_in[5];
  const float* Wv    = (const float*)d_in[6];
  const float* bv    = (const float*)d_in[7];
  const float* Wo    = (const float*)d_in[8];
  const float* bo    = (const float*)d_in[9];
  const float* gamma = (const float*)d_in[10];
  const float* beta  = (const float*)d_in[11];
  float* out = (float*)d_out;

  char* ws = (char*)d_ws;
  unsigned short* qb   = (unsigned short*)ws;                         // 8 MiB bf16 [bh][s][dk] (alpha-scaled)
  unsigned short* kbs  = (unsigned short*)(ws + ((size_t)8  << 20));  // 8 MiB bf16 chunked K
  unsigned short* vts  = (unsigned short*)(ws + ((size_t)16 << 20));  // 8 MiB bf16 chunked V^T
  unsigned short* ctxb = (unsigned short*)(ws + ((size_t)24 << 20));  // 8 MiB bf16 [b][s][hk]
  unsigned short* Wt   = (unsigned short*)(ws + ((size_t)32 << 20));  // 384 KiB bf16 [768][256]
  unsigned short* Wot  = Wt + (size_t)768 * 256;                      // 128 KiB bf16 [256][256]

  wprep<<<64, 256, 0, stream>>>(Wq, Wk, Wv, Wo, Wt, Wot);
  qkv_mfma<<<512, 384, 0, stream>>>(query, value, Wt, bq, bk, bv, qb, kbs, vts);
  attn<<<256, 256, 0, stream>>>(qb, kbs, vts, ctxb);
  oproj_ln<<<512, 256, 0, stream>>>(ctxb, Wot, bo, query, gamma, beta, out);
}